// Round 5
// baseline (171.442 us; speedup 1.0000x reference)
//
#include <hip/hip_runtime.h>
#include <math.h>

#define BQ 128
#define NQ 256
#define SMAX 300
#define CCLS 5
#define CCHG 3
#define TSTR 268          // s_tab row stride (floats), cc-major [15][268]
#define RSTR 12           // s_rows row stride (floats)
#define INFV 3.0e38f
#define NTHREADS 512

// single-instruction v_sqrt_f32
__device__ __forceinline__ float fast_sqrtf(float x) {
    return __builtin_amdgcn_sqrtf(x);
}

// pair-block shared layout (floats):
//  s_tab  : [0,4020)       15*268  (NLL table, cc-major)
//  s_cols : [4020,6068)    256*8   (pflow: pos.xyz mom.xyz en -)
//  s_rows : [6068,9140)    256*12  (particle: pos.xyz mom.xyz en cc)
//  s_part : [9140,9144)
// overlays after the post-loop barrier (tab/cols dead):
//  s_red  : [0,4096)       [16][256] row-min partials
//  s_cm   : [4224,4480)    [256] col-mins
#define SMEM_FLOATS 9156

__global__ __launch_bounds__(NTHREADS) void fused_kernel(
    const int* __restrict__ p_class, const int* __restrict__ p_charge,
    const int* __restrict__ n_particles,
    const float* __restrict__ cls_logits, const float* __restrict__ chg_logits,
    const float* __restrict__ p_pos, const float* __restrict__ pf_pos,
    const float* __restrict__ p_mom, const float* __restrict__ pf_mom,
    const float* __restrict__ p_en, const float* __restrict__ pf_en,
    const float* __restrict__ setsizes, float* __restrict__ out)
{
    __shared__ float smem[SMEM_FLOATS];
    const int t = threadIdx.x;
    const int blk = blockIdx.x;

    if (blk < BQ) {
        // ---------------- pair block: full 256x256, both min directions ----
        const int b = blk;
        const int base = b * NQ;
        float* s_tab  = smem;
        float* s_cols = smem + 4020;
        float* s_rows = smem + 6068;
        float* s_part = smem + 9140;

        if (t < NQ) {
            // build NLL table column t from pflow logits; stage pflow col data
            const int gj = base + t;
            const float* cl = cls_logits + (size_t)gj * CCLS;
            float l0=cl[0], l1=cl[1], l2=cl[2], l3=cl[3], l4=cl[4];
            float mx = fmaxf(fmaxf(fmaxf(l0,l1),fmaxf(l2,l3)),l4);
            float lse = mx + __logf(__expf(l0-mx)+__expf(l1-mx)+__expf(l2-mx)+
                                    __expf(l3-mx)+__expf(l4-mx));
            const float* gl = chg_logits + (size_t)gj * CCHG;
            float g0=gl[0], g1=gl[1], g2=gl[2];
            float gmx = fmaxf(fmaxf(g0,g1),g2);
            float glse = gmx + __logf(__expf(g0-gmx)+__expf(g1-gmx)+__expf(g2-gmx));
            float nc[CCLS] = {lse-l0, lse-l1, lse-l2, lse-l3, lse-l4};
            float ng[CCHG] = {glse-g0, glse-g1, glse-g2};
            #pragma unroll
            for (int c = 0; c < CCLS; ++c)
                #pragma unroll
                for (int g = 0; g < CCHG; ++g)
                    s_tab[(c*CCHG+g)*TSTR + t] = nc[c] + ng[g];

            float* cr = &s_cols[t*8];
            cr[0]=pf_pos[gj*3+0]; cr[1]=pf_pos[gj*3+1]; cr[2]=pf_pos[gj*3+2];
            cr[3]=pf_mom[gj*3+0]; cr[4]=pf_mom[gj*3+1]; cr[5]=pf_mom[gj*3+2];
            cr[6]=pf_en[gj];      cr[7]=0.0f;
        } else {
            // stage particle row rr
            const int rr = t - NQ;
            const int gr = base + rr;
            float* rw = &s_rows[rr*RSTR];
            rw[0]=p_pos[gr*3+0]; rw[1]=p_pos[gr*3+1]; rw[2]=p_pos[gr*3+2];
            rw[3]=p_mom[gr*3+0]; rw[4]=p_mom[gr*3+1]; rw[5]=p_mom[gr*3+2];
            rw[6]=p_en[gr];
            rw[7]=__int_as_float(p_class[gr]*CCHG + p_charge[gr]);
        }
        __syncthreads();

        const int tx = t & 31;    // row sub-index: rows p*128 + tx + 32r
        const int ty = t >> 5;    // col group: cols ty*16 + c
        const int c0 = ty * 16;

        float cmin[16];
        #pragma unroll
        for (int c = 0; c < 16; ++c) cmin[c] = INFV;
        float rmins[2][4];

        #pragma unroll
        for (int p = 0; p < 2; ++p) {
            float4 ra[4], rb[4];
            int ccr[4];
            #pragma unroll
            for (int r = 0; r < 4; ++r) {
                const int row = p*128 + tx + 32*r;
                ra[r] = *(const float4*)&s_rows[row*RSTR];
                rb[r] = *(const float4*)&s_rows[row*RSTR + 4];
                ccr[r] = __float_as_int(rb[r].w) * TSTR;
            }
            float rmin[4] = {INFV, INFV, INFV, INFV};
            #pragma unroll
            for (int c = 0; c < 16; ++c) {
                const int j = c0 + c;
                const float4 cd0 = *(const float4*)&s_cols[j*8];     // broadcast
                const float4 cd1 = *(const float4*)&s_cols[j*8+4];   // broadcast
                float cm = cmin[c];
                #pragma unroll
                for (int r = 0; r < 4; ++r) {
                    float dx=ra[r].x-cd0.x, dy=ra[r].y-cd0.y, dz=ra[r].z-cd0.z;
                    float ex=ra[r].w-cd0.w, ey=rb[r].x-cd1.x, ez=rb[r].y-cd1.y;
                    float de=rb[r].z-cd1.z;
                    float v = s_tab[ccr[r] + j]                      // b32, <=15 rows
                            + fast_sqrtf(dx*dx + dy*dy + dz*dz)
                            + fast_sqrtf(ex*ex + ey*ey + ez*ez)
                            + de*de;
                    rmin[r] = fminf(rmin[r], v);
                    cm = fminf(cm, v);
                }
                cmin[c] = cm;
            }
            #pragma unroll
            for (int r = 0; r < 4; ++r) rmins[p][r] = rmin[r];
        }

        __syncthreads();               // tab/cols/rows reads done -> overlay ok
        float* s_red = smem;           // [16][256]
        float* s_cm  = smem + 4224;    // [256]

        // col-min: reduce over tx (contiguous 32-lane subgroups)
        #pragma unroll
        for (int c = 0; c < 16; ++c) {
            float v = cmin[c];
            #pragma unroll
            for (int off = 16; off > 0; off >>= 1)
                v = fminf(v, __shfl_down(v, off, 32));
            if (tx == 0) s_cm[c0 + c] = v;
        }
        // row-min partials: [ty][row]
        #pragma unroll
        for (int r = 0; r < 4; ++r) {
            s_red[ty*256 + tx + 32*r]        = rmins[0][r];
            s_red[ty*256 + 128 + tx + 32*r]  = rmins[1][r];
        }
        __syncthreads();
        if (t < NQ) {
            float m = s_red[t];
            #pragma unroll
            for (int k = 1; k < 16; ++k) m = fminf(m, s_red[k*256 + t]);
            float su = m + s_cm[t];    // particle-side min + pflow-side min
            #pragma unroll
            for (int off = 32; off > 0; off >>= 1) su += __shfl_down(su, off, 64);
            if ((t & 63) == 0) s_part[t >> 6] = su;
        }
        __syncthreads();
        if (t == 0)
            atomicAdd(out, (s_part[0]+s_part[1]+s_part[2]+s_part[3]) * (1.0f/BQ));

    } else {
        // ---------------- set-size block (one per batch) ----------------
        const int b = blk - BQ;
        float* s_ss = smem;          // [2][304]
        float* s_m  = smem + 608;    // [304]
        float* s_p5 = smem + 912;    // [8]
        float* s_one= smem + 920;

        const int slice = t >> 8;    // 0/1 -> rows slice*128..+128
        const int col = t & 255;
        const float* bp = setsizes + (size_t)b * NQ * SMAX + (size_t)(slice*128) * SMAX;
        {
            const float* p = bp + col;
            float acc = 0.f;
            #pragma unroll 16
            for (int i = 0; i < 128; ++i) acc += p[(size_t)i * SMAX];
            s_ss[slice*304 + col] = acc;
        }
        if (col < SMAX - NQ) {       // cols 256..299
            const float* p = bp + (NQ + col);
            float acc = 0.f;
            #pragma unroll 16
            for (int i = 0; i < 128; ++i) acc += p[(size_t)i * SMAX];
            s_ss[slice*304 + NQ + col] = acc;
        }
        __syncthreads();
        float m = -INFV;
        if (t < SMAX) { m = (s_ss[t] + s_ss[304 + t]) * (1.0f / NQ); s_m[t] = m; }
        const int wave = t >> 6, lane = t & 63;
        float wm = m;
        #pragma unroll
        for (int off = 32; off > 0; off >>= 1) wm = fmaxf(wm, __shfl_down(wm, off));
        if (lane == 0 && wave < 5) s_p5[wave] = wm;
        __syncthreads();
        if (t == 0)
            s_one[0] = fmaxf(fmaxf(fmaxf(s_p5[0], s_p5[1]), fmaxf(s_p5[2], s_p5[3])), s_p5[4]);
        __syncthreads();
        const float mx = s_one[0];
        float e = (t < SMAX) ? __expf(m - mx) : 0.f;
        #pragma unroll
        for (int off = 32; off > 0; off >>= 1) e += __shfl_down(e, off);
        if (lane == 0 && wave < 5) s_p5[wave] = e;
        __syncthreads();
        if (t == 0) {
            float s = s_p5[0] + s_p5[1] + s_p5[2] + s_p5[3] + s_p5[4];
            int nb = n_particles[b];
            float loss = -(s_m[nb] - mx - __logf(s));
            atomicAdd(out, loss * (1.0f / BQ));
        }
    }
}

extern "C" void kernel_launch(void* const* d_in, const int* in_sizes, int n_in,
                              void* d_out, int out_size, void* d_ws, size_t ws_size,
                              hipStream_t stream) {
    (void)in_sizes; (void)n_in; (void)d_ws; (void)ws_size;
    const int*   p_class     = (const int*)d_in[0];
    const int*   p_charge    = (const int*)d_in[1];
    const int*   n_particles = (const int*)d_in[2];
    const float* cls_logits  = (const float*)d_in[3];
    const float* chg_logits  = (const float*)d_in[4];
    const float* p_pos       = (const float*)d_in[5];
    const float* pf_pos      = (const float*)d_in[6];
    const float* p_mom       = (const float*)d_in[7];
    const float* pf_mom      = (const float*)d_in[8];
    const float* p_en        = (const float*)d_in[9];
    const float* pf_en       = (const float*)d_in[10];
    const float* setsizes    = (const float*)d_in[11];
    float* out = (float*)d_out;

    (void)hipMemsetAsync(out, 0, sizeof(float) * (size_t)out_size, stream);

    fused_kernel<<<2 * BQ, NTHREADS, 0, stream>>>(
        p_class, p_charge, n_particles, cls_logits, chg_logits,
        p_pos, pf_pos, p_mom, pf_mom, p_en, pf_en, setsizes, out);
}

// Round 6
// 169.052 us; speedup vs baseline: 1.0141x; 1.0141x over previous
//
#include <hip/hip_runtime.h>
#include <math.h>

#define BQ 128
#define NQ 256
#define SMAX 300
#define CCLS 5
#define CCHG 3
#define TSTR 268          // s_tab row stride (floats), cc-major [15][268]
#define RSTR 12           // s_rows row stride (floats)
#define INFV 3.0e38f
#define NTHREADS 512

// single-instruction v_sqrt_f32
__device__ __forceinline__ float fast_sqrtf(float x) {
    return __builtin_amdgcn_sqrtf(x);
}

// pair-block shared layout (floats):
//  s_tab  : [0,4020)       15*268  (NLL table, cc-major)
//  s_cols : [4020,6068)    256*8   (pflow: pos.xyz mom.xyz en -)
//  s_rows : [6068,9140)    256*12  (particle: pos.xyz mom.xyz en cc)
//  s_part : [9140,9144)
// overlays after the post-loop barrier (tab/cols dead):
//  s_red  : [0,4096)       [16][256] row-min partials
//  s_cm   : [4224,4480)    [256] col-mins
#define SMEM_FLOATS 9156

// __launch_bounds__(512, 2): 2 waves/EU min -> VGPR cap 256. R5 used the
// one-arg form; compiler targeted 128 VGPRs and spilled ~480 B/thread to
// scratch (WRITE_SIZE 63 MB, VALUBusy 6%, kernel 82 us, fully spill-bound).
__global__ __launch_bounds__(NTHREADS, 2) void fused_kernel(
    const int* __restrict__ p_class, const int* __restrict__ p_charge,
    const int* __restrict__ n_particles,
    const float* __restrict__ cls_logits, const float* __restrict__ chg_logits,
    const float* __restrict__ p_pos, const float* __restrict__ pf_pos,
    const float* __restrict__ p_mom, const float* __restrict__ pf_mom,
    const float* __restrict__ p_en, const float* __restrict__ pf_en,
    const float* __restrict__ setsizes, float* __restrict__ out)
{
    __shared__ float smem[SMEM_FLOATS];
    const int t = threadIdx.x;
    const int blk = blockIdx.x;

    if (blk < BQ) {
        // ---------------- pair block: full 256x256, both min directions ----
        const int b = blk;
        const int base = b * NQ;
        float* s_tab  = smem;
        float* s_cols = smem + 4020;
        float* s_rows = smem + 6068;
        float* s_part = smem + 9140;

        if (t < NQ) {
            // build NLL table column t from pflow logits; stage pflow col data
            const int gj = base + t;
            const float* cl = cls_logits + (size_t)gj * CCLS;
            float l0=cl[0], l1=cl[1], l2=cl[2], l3=cl[3], l4=cl[4];
            float mx = fmaxf(fmaxf(fmaxf(l0,l1),fmaxf(l2,l3)),l4);
            float lse = mx + __logf(__expf(l0-mx)+__expf(l1-mx)+__expf(l2-mx)+
                                    __expf(l3-mx)+__expf(l4-mx));
            const float* gl = chg_logits + (size_t)gj * CCHG;
            float g0=gl[0], g1=gl[1], g2=gl[2];
            float gmx = fmaxf(fmaxf(g0,g1),g2);
            float glse = gmx + __logf(__expf(g0-gmx)+__expf(g1-gmx)+__expf(g2-gmx));
            float nc[CCLS] = {lse-l0, lse-l1, lse-l2, lse-l3, lse-l4};
            float ng[CCHG] = {glse-g0, glse-g1, glse-g2};
            #pragma unroll
            for (int c = 0; c < CCLS; ++c)
                #pragma unroll
                for (int g = 0; g < CCHG; ++g)
                    s_tab[(c*CCHG+g)*TSTR + t] = nc[c] + ng[g];

            float* cr = &s_cols[t*8];
            cr[0]=pf_pos[gj*3+0]; cr[1]=pf_pos[gj*3+1]; cr[2]=pf_pos[gj*3+2];
            cr[3]=pf_mom[gj*3+0]; cr[4]=pf_mom[gj*3+1]; cr[5]=pf_mom[gj*3+2];
            cr[6]=pf_en[gj];      cr[7]=0.0f;
        } else {
            // stage particle row rr
            const int rr = t - NQ;
            const int gr = base + rr;
            float* rw = &s_rows[rr*RSTR];
            rw[0]=p_pos[gr*3+0]; rw[1]=p_pos[gr*3+1]; rw[2]=p_pos[gr*3+2];
            rw[3]=p_mom[gr*3+0]; rw[4]=p_mom[gr*3+1]; rw[5]=p_mom[gr*3+2];
            rw[6]=p_en[gr];
            rw[7]=__int_as_float(p_class[gr]*CCHG + p_charge[gr]);
        }
        __syncthreads();

        const int tx = t & 31;    // row sub-index: rows p*128 + tx + 32r
        const int ty = t >> 5;    // col group: cols ty*16 + c
        const int c0 = ty * 16;

        float cmin[16];
        #pragma unroll
        for (int c = 0; c < 16; ++c) cmin[c] = INFV;
        float rmins[2][4];

        #pragma unroll
        for (int p = 0; p < 2; ++p) {
            float4 ra[4], rb[4];
            int ccr[4];
            #pragma unroll
            for (int r = 0; r < 4; ++r) {
                const int row = p*128 + tx + 32*r;
                ra[r] = *(const float4*)&s_rows[row*RSTR];
                rb[r] = *(const float4*)&s_rows[row*RSTR + 4];
                ccr[r] = __float_as_int(rb[r].w) * TSTR;
            }
            float rmin[4] = {INFV, INFV, INFV, INFV};
            #pragma unroll
            for (int c = 0; c < 16; ++c) {
                const int j = c0 + c;
                const float4 cd0 = *(const float4*)&s_cols[j*8];     // broadcast
                const float4 cd1 = *(const float4*)&s_cols[j*8+4];   // broadcast
                float cm = cmin[c];
                #pragma unroll
                for (int r = 0; r < 4; ++r) {
                    float dx=ra[r].x-cd0.x, dy=ra[r].y-cd0.y, dz=ra[r].z-cd0.z;
                    float ex=ra[r].w-cd0.w, ey=rb[r].x-cd1.x, ez=rb[r].y-cd1.y;
                    float de=rb[r].z-cd1.z;
                    float v = s_tab[ccr[r] + j]                      // b32, <=15 rows
                            + fast_sqrtf(dx*dx + dy*dy + dz*dz)
                            + fast_sqrtf(ex*ex + ey*ey + ez*ez)
                            + de*de;
                    rmin[r] = fminf(rmin[r], v);
                    cm = fminf(cm, v);
                }
                cmin[c] = cm;
            }
            #pragma unroll
            for (int r = 0; r < 4; ++r) rmins[p][r] = rmin[r];
        }

        __syncthreads();               // tab/cols/rows reads done -> overlay ok
        float* s_red = smem;           // [16][256]
        float* s_cm  = smem + 4224;    // [256]

        // col-min: reduce over tx (contiguous 32-lane subgroups)
        #pragma unroll
        for (int c = 0; c < 16; ++c) {
            float v = cmin[c];
            #pragma unroll
            for (int off = 16; off > 0; off >>= 1)
                v = fminf(v, __shfl_down(v, off, 32));
            if (tx == 0) s_cm[c0 + c] = v;
        }
        // row-min partials: [ty][row]
        #pragma unroll
        for (int r = 0; r < 4; ++r) {
            s_red[ty*256 + tx + 32*r]        = rmins[0][r];
            s_red[ty*256 + 128 + tx + 32*r]  = rmins[1][r];
        }
        __syncthreads();
        if (t < NQ) {
            float m = s_red[t];
            #pragma unroll
            for (int k = 1; k < 16; ++k) m = fminf(m, s_red[k*256 + t]);
            float su = m + s_cm[t];    // particle-side min + pflow-side min
            #pragma unroll
            for (int off = 32; off > 0; off >>= 1) su += __shfl_down(su, off, 64);
            if ((t & 63) == 0) s_part[t >> 6] = su;
        }
        __syncthreads();
        if (t == 0)
            atomicAdd(out, (s_part[0]+s_part[1]+s_part[2]+s_part[3]) * (1.0f/BQ));

    } else {
        // ---------------- set-size block (one per batch) ----------------
        const int b = blk - BQ;
        float* s_ss = smem;          // [2][304]
        float* s_m  = smem + 608;    // [304]
        float* s_p5 = smem + 912;    // [8]
        float* s_one= smem + 920;

        const int slice = t >> 8;    // 0/1 -> rows slice*128..+128
        const int col = t & 255;
        const float* bp = setsizes + (size_t)b * NQ * SMAX + (size_t)(slice*128) * SMAX;
        {
            const float* p = bp + col;
            float acc = 0.f;
            #pragma unroll 16
            for (int i = 0; i < 128; ++i) acc += p[(size_t)i * SMAX];
            s_ss[slice*304 + col] = acc;
        }
        if (col < SMAX - NQ) {       // cols 256..299
            const float* p = bp + (NQ + col);
            float acc = 0.f;
            #pragma unroll 16
            for (int i = 0; i < 128; ++i) acc += p[(size_t)i * SMAX];
            s_ss[slice*304 + NQ + col] = acc;
        }
        __syncthreads();
        float m = -INFV;
        if (t < SMAX) { m = (s_ss[t] + s_ss[304 + t]) * (1.0f / NQ); s_m[t] = m; }
        const int wave = t >> 6, lane = t & 63;
        float wm = m;
        #pragma unroll
        for (int off = 32; off > 0; off >>= 1) wm = fmaxf(wm, __shfl_down(wm, off));
        if (lane == 0 && wave < 5) s_p5[wave] = wm;
        __syncthreads();
        if (t == 0)
            s_one[0] = fmaxf(fmaxf(fmaxf(s_p5[0], s_p5[1]), fmaxf(s_p5[2], s_p5[3])), s_p5[4]);
        __syncthreads();
        const float mx = s_one[0];
        float e = (t < SMAX) ? __expf(m - mx) : 0.f;
        #pragma unroll
        for (int off = 32; off > 0; off >>= 1) e += __shfl_down(e, off);
        if (lane == 0 && wave < 5) s_p5[wave] = e;
        __syncthreads();
        if (t == 0) {
            float s = s_p5[0] + s_p5[1] + s_p5[2] + s_p5[3] + s_p5[4];
            int nb = n_particles[b];
            float loss = -(s_m[nb] - mx - __logf(s));
            atomicAdd(out, loss * (1.0f / BQ));
        }
    }
}

extern "C" void kernel_launch(void* const* d_in, const int* in_sizes, int n_in,
                              void* d_out, int out_size, void* d_ws, size_t ws_size,
                              hipStream_t stream) {
    (void)in_sizes; (void)n_in; (void)d_ws; (void)ws_size;
    const int*   p_class     = (const int*)d_in[0];
    const int*   p_charge    = (const int*)d_in[1];
    const int*   n_particles = (const int*)d_in[2];
    const float* cls_logits  = (const float*)d_in[3];
    const float* chg_logits  = (const float*)d_in[4];
    const float* p_pos       = (const float*)d_in[5];
    const float* pf_pos      = (const float*)d_in[6];
    const float* p_mom       = (const float*)d_in[7];
    const float* pf_mom      = (const float*)d_in[8];
    const float* p_en        = (const float*)d_in[9];
    const float* pf_en       = (const float*)d_in[10];
    const float* setsizes    = (const float*)d_in[11];
    float* out = (float*)d_out;

    (void)hipMemsetAsync(out, 0, sizeof(float) * (size_t)out_size, stream);

    fused_kernel<<<2 * BQ, NTHREADS, 0, stream>>>(
        p_class, p_charge, n_particles, cls_logits, chg_logits,
        p_pos, pf_pos, p_mom, pf_mom, p_en, pf_en, setsizes, out);
}

// Round 7
// 123.102 us; speedup vs baseline: 1.3927x; 1.3733x over previous
//
#include <hip/hip_runtime.h>
#include <math.h>

#define BQ 128
#define NQ 256
#define SMAX 300
#define SPAD 304
#define CCLS 5
#define CCHG 3
#define TSTR 268          // s_tab row stride (floats), cc-major [15][268]
#define RSTR 12           // s_rows row stride (floats)
#define INFV 3.0e38f

__device__ __forceinline__ float fast_sqrtf(float x) {
    return __builtin_amdgcn_sqrtf(x);
}

// ---------------------------------------------------------------------------
// Pair kernel: 128 blocks x 512 threads. Full 256x256 pair tile per batch;
// both min directions in one pass (each pair computed once).
// No LDS overlays (s_red has its own region) so the p-loop needs no barrier
// and stays #pragma unroll 1 -> small live set, no spills (R5/R6: 63 MB
// scratch writes from the fully-unrolled variant).
// LDS: 4020+2048+3072+4096+256+4 = 13496 floats = 54 KB -> 2 blocks/CU.
// ---------------------------------------------------------------------------
#define P_TAB   0
#define P_COLS  4020
#define P_ROWS  6068
#define P_RED   9140
#define P_CM    13236
#define P_PART  13492
#define P_FLOATS 13496

__global__ __launch_bounds__(512, 2) void pair_kernel(
    const int* __restrict__ p_class, const int* __restrict__ p_charge,
    const float* __restrict__ cls_logits, const float* __restrict__ chg_logits,
    const float* __restrict__ p_pos, const float* __restrict__ pf_pos,
    const float* __restrict__ p_mom, const float* __restrict__ pf_mom,
    const float* __restrict__ p_en, const float* __restrict__ pf_en,
    float* __restrict__ out)
{
    __shared__ float smem[P_FLOATS];
    const int t = threadIdx.x;
    const int b = blockIdx.x;
    const int base = b * NQ;
    float* s_tab  = smem + P_TAB;
    float* s_cols = smem + P_COLS;
    float* s_rows = smem + P_ROWS;
    float* s_red  = smem + P_RED;
    float* s_cm   = smem + P_CM;
    float* s_part = smem + P_PART;

    if (t < NQ) {
        // NLL table column t (pflow logits) + pflow col data
        const int gj = base + t;
        const float* cl = cls_logits + (size_t)gj * CCLS;
        float l0=cl[0], l1=cl[1], l2=cl[2], l3=cl[3], l4=cl[4];
        float mx = fmaxf(fmaxf(fmaxf(l0,l1),fmaxf(l2,l3)),l4);
        float lse = mx + __logf(__expf(l0-mx)+__expf(l1-mx)+__expf(l2-mx)+
                                __expf(l3-mx)+__expf(l4-mx));
        const float* gl = chg_logits + (size_t)gj * CCHG;
        float g0=gl[0], g1=gl[1], g2=gl[2];
        float gmx = fmaxf(fmaxf(g0,g1),g2);
        float glse = gmx + __logf(__expf(g0-gmx)+__expf(g1-gmx)+__expf(g2-gmx));
        float nc[CCLS] = {lse-l0, lse-l1, lse-l2, lse-l3, lse-l4};
        float ng[CCHG] = {glse-g0, glse-g1, glse-g2};
        #pragma unroll
        for (int c = 0; c < CCLS; ++c)
            #pragma unroll
            for (int g = 0; g < CCHG; ++g)
                s_tab[(c*CCHG+g)*TSTR + t] = nc[c] + ng[g];

        float* cr = &s_cols[t*8];
        cr[0]=pf_pos[gj*3+0]; cr[1]=pf_pos[gj*3+1]; cr[2]=pf_pos[gj*3+2];
        cr[3]=pf_mom[gj*3+0]; cr[4]=pf_mom[gj*3+1]; cr[5]=pf_mom[gj*3+2];
        cr[6]=pf_en[gj];      cr[7]=0.0f;
    } else {
        // particle row rr
        const int rr = t - NQ;
        const int gr = base + rr;
        float* rw = &s_rows[rr*RSTR];
        rw[0]=p_pos[gr*3+0]; rw[1]=p_pos[gr*3+1]; rw[2]=p_pos[gr*3+2];
        rw[3]=p_mom[gr*3+0]; rw[4]=p_mom[gr*3+1]; rw[5]=p_mom[gr*3+2];
        rw[6]=p_en[gr];
        rw[7]=__int_as_float(p_class[gr]*CCHG + p_charge[gr]);
    }
    __syncthreads();

    const int tx = t & 31;    // row sub-index: rows p*128 + tx + 32r
    const int ty = t >> 5;    // col group: cols ty*16 + c
    const int c0 = ty * 16;

    float cmin[16];
    #pragma unroll
    for (int c = 0; c < 16; ++c) cmin[c] = INFV;

    #pragma unroll 1
    for (int p = 0; p < 2; ++p) {
        float4 ra[4], rb[4];
        int ccr[4];
        #pragma unroll
        for (int r = 0; r < 4; ++r) {
            const int row = p*128 + tx + 32*r;
            ra[r] = *(const float4*)&s_rows[row*RSTR];
            rb[r] = *(const float4*)&s_rows[row*RSTR + 4];
            ccr[r] = __float_as_int(rb[r].w) * TSTR;
        }
        float rmin[4] = {INFV, INFV, INFV, INFV};
        #pragma unroll 4
        for (int c = 0; c < 16; ++c) {
            const int j = c0 + c;
            const float4 cd0 = *(const float4*)&s_cols[j*8];     // broadcast
            const float4 cd1 = *(const float4*)&s_cols[j*8+4];   // broadcast
            float cm = cmin[c];
            #pragma unroll
            for (int r = 0; r < 4; ++r) {
                float dx=ra[r].x-cd0.x, dy=ra[r].y-cd0.y, dz=ra[r].z-cd0.z;
                float ex=ra[r].w-cd0.w, ey=rb[r].x-cd1.x, ez=rb[r].y-cd1.y;
                float de=rb[r].z-cd1.z;
                float v = s_tab[ccr[r] + j]                      // <=15 rows, bcast
                        + fast_sqrtf(dx*dx + dy*dy + dz*dz)
                        + fast_sqrtf(ex*ex + ey*ey + ez*ez)
                        + de*de;
                rmin[r] = fminf(rmin[r], v);
                cm = fminf(cm, v);
            }
            cmin[c] = cm;
        }
        // row-min partials straight to (dedicated) LDS — no overlay, no array
        #pragma unroll
        for (int r = 0; r < 4; ++r)
            s_red[ty*256 + p*128 + tx + 32*r] = rmin[r];
    }

    // col-min: reduce over tx (contiguous 32-lane subgroups)
    #pragma unroll 4
    for (int c = 0; c < 16; ++c) {
        float v = cmin[c];
        #pragma unroll
        for (int off = 16; off > 0; off >>= 1)
            v = fminf(v, __shfl_down(v, off, 32));
        if (tx == 0) s_cm[c0 + c] = v;
    }
    __syncthreads();

    if (t < NQ) {
        float m = s_red[t];
        #pragma unroll
        for (int k = 1; k < 16; ++k) m = fminf(m, s_red[k*256 + t]);
        float su = m + s_cm[t];        // particle-side min + pflow-side min
        #pragma unroll
        for (int off = 32; off > 0; off >>= 1) su += __shfl_down(su, off, 64);
        if ((t & 63) == 0) s_part[t >> 6] = su;
    }
    __syncthreads();
    if (t == 0)
        atomicAdd(out, (s_part[0]+s_part[1]+s_part[2]+s_part[3]) * (1.0f/BQ));
}

// ---------------------------------------------------------------------------
// Set-size partial column sums: 1024 blocks (128 batches x 8 chunks of 32
// rows) x 320 threads. 20 waves/CU -> HBM-saturating stream of 39.3 MB.
// ---------------------------------------------------------------------------
__global__ __launch_bounds__(320) void ss_partial(
    const float* __restrict__ ss, float* __restrict__ ws)
{
    const int blk = blockIdx.x;
    const int b = blk >> 3;
    const int ch = blk & 7;
    const int t = threadIdx.x;
    if (t >= SMAX) return;
    const float* p = ss + ((size_t)b * NQ + (size_t)ch * 32) * SMAX + t;
    float acc = 0.f;
    #pragma unroll 8
    for (int i = 0; i < 32; ++i) acc += p[(size_t)i * SMAX];
    ws[blk * SPAD + t] = acc;
}

// ---------------------------------------------------------------------------
// Set-size finisher: 128 blocks x 320. Combine 8 partials, log-softmax, NLL.
// nchunk==0: direct fallback (no ws).
// ---------------------------------------------------------------------------
__global__ __launch_bounds__(320) void ss_final(
    const float* __restrict__ ss, const float* __restrict__ ws,
    const int* __restrict__ n_particles, float* __restrict__ out, int nchunk)
{
    const int b = blockIdx.x;
    const int t = threadIdx.x;
    __shared__ float s_m[SMAX];
    __shared__ float s_p5[8];
    __shared__ float s_one[1];

    float m = -INFV;
    if (t < SMAX) {
        float acc = 0.f;
        if (nchunk > 0) {
            #pragma unroll
            for (int c = 0; c < 8; ++c) acc += ws[(b*8 + c) * SPAD + t];
        } else {
            const float* p = ss + (size_t)b * NQ * SMAX + t;
            #pragma unroll 8
            for (int i = 0; i < NQ; ++i) acc += p[(size_t)i * SMAX];
        }
        m = acc * (1.0f / NQ);
        s_m[t] = m;
    }
    const int wave = t >> 6, lane = t & 63;
    float wm = m;
    #pragma unroll
    for (int off = 32; off > 0; off >>= 1) wm = fmaxf(wm, __shfl_down(wm, off));
    if (lane == 0) s_p5[wave] = wm;
    __syncthreads();
    if (t == 0)
        s_one[0] = fmaxf(fmaxf(fmaxf(s_p5[0], s_p5[1]), fmaxf(s_p5[2], s_p5[3])), s_p5[4]);
    __syncthreads();
    const float mx = s_one[0];
    float e = (t < SMAX) ? __expf(m - mx) : 0.f;
    #pragma unroll
    for (int off = 32; off > 0; off >>= 1) e += __shfl_down(e, off);
    if (lane == 0) s_p5[wave] = e;
    __syncthreads();
    if (t == 0) {
        float s = s_p5[0] + s_p5[1] + s_p5[2] + s_p5[3] + s_p5[4];
        int nb = n_particles[b];
        float loss = -(s_m[nb] - mx - __logf(s));
        atomicAdd(out, loss * (1.0f / BQ));
    }
}

extern "C" void kernel_launch(void* const* d_in, const int* in_sizes, int n_in,
                              void* d_out, int out_size, void* d_ws, size_t ws_size,
                              hipStream_t stream) {
    (void)in_sizes; (void)n_in;
    const int*   p_class     = (const int*)d_in[0];
    const int*   p_charge    = (const int*)d_in[1];
    const int*   n_particles = (const int*)d_in[2];
    const float* cls_logits  = (const float*)d_in[3];
    const float* chg_logits  = (const float*)d_in[4];
    const float* p_pos       = (const float*)d_in[5];
    const float* pf_pos      = (const float*)d_in[6];
    const float* p_mom       = (const float*)d_in[7];
    const float* pf_mom      = (const float*)d_in[8];
    const float* p_en        = (const float*)d_in[9];
    const float* pf_en       = (const float*)d_in[10];
    const float* setsizes    = (const float*)d_in[11];
    float* out = (float*)d_out;
    float* ws  = (float*)d_ws;

    (void)hipMemsetAsync(out, 0, sizeof(float) * (size_t)out_size, stream);

    const bool use_ws = ws_size >= (size_t)1024 * SPAD * sizeof(float);
    if (use_ws) ss_partial<<<1024, 320, 0, stream>>>(setsizes, ws);

    pair_kernel<<<BQ, 512, 0, stream>>>(p_class, p_charge, cls_logits, chg_logits,
                                        p_pos, pf_pos, p_mom, pf_mom, p_en, pf_en, out);

    ss_final<<<BQ, 320, 0, stream>>>(setsizes, ws, n_particles, out, use_ws ? 8 : 0);
}

// Round 8
// 111.344 us; speedup vs baseline: 1.5397x; 1.1056x over previous
//
#include <hip/hip_runtime.h>
#include <math.h>

#define BQ 128
#define NQ 256
#define SMAX 300
#define CCLS 5
#define CCHG 3
#define TSTR 268          // s_tab row stride (floats), cc-major [15][268]
#define RSTR 12           // s_rows row stride (floats)
#define INFV 3.0e38f

#define NPAIR 256         // 128 batches x 2 row-halves
#define NMAIN (NPAIR + BQ)

__device__ __forceinline__ float fast_sqrtf(float x) {
    return __builtin_amdgcn_sqrtf(x);
}

// pair-block LDS (floats):
//  s_tab  : [0,4020)      15*268 NLL table (cc-major)
//  s_cols : [4020,6068)   256*8  pflow pos/mom/en
//  s_rows : [6068,7604)   128*12 particle rows of this half
//  s_red  : [7604,9652)   [16][128] row-min partials over ty
//  s_part : [9652,9656)
// ss blocks reuse the front of the same array (~1 KB).
#define P_TAB   0
#define P_COLS  4020
#define P_ROWS  6068
#define P_RED   7604
#define P_PART  9652
#define SMEM_FLOATS 9656

// ws: col-min partials, ws[blk*256 + j], blk = b*2 + rowhalf  (256 KB)

__global__ __launch_bounds__(512, 2) void main_kernel(
    const int* __restrict__ p_class, const int* __restrict__ p_charge,
    const int* __restrict__ n_particles,
    const float* __restrict__ cls_logits, const float* __restrict__ chg_logits,
    const float* __restrict__ p_pos, const float* __restrict__ pf_pos,
    const float* __restrict__ p_mom, const float* __restrict__ pf_mom,
    const float* __restrict__ p_en, const float* __restrict__ pf_en,
    const float* __restrict__ setsizes, float* __restrict__ ws,
    float* __restrict__ out)
{
    __shared__ float smem[SMEM_FLOATS];
    const int t = threadIdx.x;
    const int blk = blockIdx.x;

    if (blk < NPAIR) {
        // ---------------- pair block: 128 rows x 256 cols ----------------
        const int b  = blk >> 1;
        const int rh = blk & 1;
        const int base = b * NQ;
        float* s_tab  = smem + P_TAB;
        float* s_cols = smem + P_COLS;
        float* s_rows = smem + P_ROWS;
        float* s_red  = smem + P_RED;
        float* s_part = smem + P_PART;

        if (t < NQ) {
            // NLL table column t (pflow logits) + pflow col data
            const int gj = base + t;
            const float* cl = cls_logits + (size_t)gj * CCLS;
            float l0=cl[0], l1=cl[1], l2=cl[2], l3=cl[3], l4=cl[4];
            float mx = fmaxf(fmaxf(fmaxf(l0,l1),fmaxf(l2,l3)),l4);
            float lse = mx + __logf(__expf(l0-mx)+__expf(l1-mx)+__expf(l2-mx)+
                                    __expf(l3-mx)+__expf(l4-mx));
            const float* gl = chg_logits + (size_t)gj * CCHG;
            float g0=gl[0], g1=gl[1], g2=gl[2];
            float gmx = fmaxf(fmaxf(g0,g1),g2);
            float glse = gmx + __logf(__expf(g0-gmx)+__expf(g1-gmx)+__expf(g2-gmx));
            float nc[CCLS] = {lse-l0, lse-l1, lse-l2, lse-l3, lse-l4};
            float ng[CCHG] = {glse-g0, glse-g1, glse-g2};
            #pragma unroll
            for (int c = 0; c < CCLS; ++c)
                #pragma unroll
                for (int g = 0; g < CCHG; ++g)
                    s_tab[(c*CCHG+g)*TSTR + t] = nc[c] + ng[g];

            float* cr = &s_cols[t*8];
            cr[0]=pf_pos[gj*3+0]; cr[1]=pf_pos[gj*3+1]; cr[2]=pf_pos[gj*3+2];
            cr[3]=pf_mom[gj*3+0]; cr[4]=pf_mom[gj*3+1]; cr[5]=pf_mom[gj*3+2];
            cr[6]=pf_en[gj];      cr[7]=0.0f;
        } else if (t < NQ + 128) {
            // particle row rr of this half
            const int rr = t - NQ;
            const int gr = base + rh*128 + rr;
            float* rw = &s_rows[rr*RSTR];
            rw[0]=p_pos[gr*3+0]; rw[1]=p_pos[gr*3+1]; rw[2]=p_pos[gr*3+2];
            rw[3]=p_mom[gr*3+0]; rw[4]=p_mom[gr*3+1]; rw[5]=p_mom[gr*3+2];
            rw[6]=p_en[gr];
            rw[7]=__int_as_float(p_class[gr]*CCHG + p_charge[gr]);
        }
        __syncthreads();

        const int tx = t & 31;    // local rows tx + 32r, r<4
        const int ty = t >> 5;    // cols ty*16 + c
        const int c0 = ty * 16;

        float4 ra[4], rb[4];
        int ccr[4];
        #pragma unroll
        for (int r = 0; r < 4; ++r) {
            const int row = tx + 32*r;
            ra[r] = *(const float4*)&s_rows[row*RSTR];
            rb[r] = *(const float4*)&s_rows[row*RSTR + 4];
            ccr[r] = __float_as_int(rb[r].w) * TSTR;
        }
        float cmin[16];
        #pragma unroll
        for (int c = 0; c < 16; ++c) cmin[c] = INFV;
        float rmin[4] = {INFV, INFV, INFV, INFV};

        #pragma unroll 4
        for (int c = 0; c < 16; ++c) {
            const int j = c0 + c;
            const float4 cd0 = *(const float4*)&s_cols[j*8];     // half-wave bcast
            const float4 cd1 = *(const float4*)&s_cols[j*8+4];
            float cm = cmin[c];
            #pragma unroll
            for (int r = 0; r < 4; ++r) {
                float dx=ra[r].x-cd0.x, dy=ra[r].y-cd0.y, dz=ra[r].z-cd0.z;
                float ex=ra[r].w-cd0.w, ey=rb[r].x-cd1.x, ez=rb[r].y-cd1.y;
                float de=rb[r].z-cd1.z;
                float v = s_tab[ccr[r] + j]                      // <=15 rows, bcast
                        + fast_sqrtf(dx*dx + dy*dy + dz*dz)
                        + fast_sqrtf(ex*ex + ey*ey + ez*ez)
                        + de*de;
                rmin[r] = fminf(rmin[r], v);
                cm = fminf(cm, v);
            }
            cmin[c] = cm;
        }

        // col-min partials (over this row-half) -> ws
        #pragma unroll 4
        for (int c = 0; c < 16; ++c) {
            float v = cmin[c];
            #pragma unroll
            for (int off = 16; off > 0; off >>= 1)
                v = fminf(v, __shfl_down(v, off, 32));
            if (tx == 0) ws[blk*NQ + c0 + c] = v;
        }
        // row-min partials over ty -> LDS
        #pragma unroll
        for (int r = 0; r < 4; ++r)
            s_red[ty*128 + tx + 32*r] = rmin[r];
        __syncthreads();

        if (t < 128) {
            float m = s_red[t];
            #pragma unroll
            for (int k = 1; k < 16; ++k) m = fminf(m, s_red[k*128 + t]);
            #pragma unroll
            for (int off = 32; off > 0; off >>= 1) m += __shfl_down(m, off, 64);
            if ((t & 63) == 0) s_part[t >> 6] = m;
        }
        __syncthreads();
        if (t == 0)
            atomicAdd(out, (s_part[0] + s_part[1]) * (1.0f / BQ));

    } else {
        // ---------------- set-size block (one per batch, complete) --------
        const int b = blk - NPAIR;
        float* s_ss = smem;          // [2][304]
        float* s_m  = smem + 608;    // [304]
        float* s_p5 = smem + 912;    // [8]
        float* s_one= smem + 920;

        const int slice = t >> 8;    // 0/1 -> rows slice*128..+128
        const int col = t & 255;
        const float* bp = setsizes + (size_t)b * NQ * SMAX + (size_t)(slice*128) * SMAX;
        {
            const float* p = bp + col;
            float acc = 0.f;
            #pragma unroll 16
            for (int i = 0; i < 128; ++i) acc += p[(size_t)i * SMAX];
            s_ss[slice*304 + col] = acc;
        }
        if (col < SMAX - NQ) {       // cols 256..299
            const float* p = bp + (NQ + col);
            float acc = 0.f;
            #pragma unroll 16
            for (int i = 0; i < 128; ++i) acc += p[(size_t)i * SMAX];
            s_ss[slice*304 + NQ + col] = acc;
        }
        __syncthreads();
        float m = -INFV;
        if (t < SMAX) { m = (s_ss[t] + s_ss[304 + t]) * (1.0f / NQ); s_m[t] = m; }
        const int wave = t >> 6, lane = t & 63;
        float wm = m;
        #pragma unroll
        for (int off = 32; off > 0; off >>= 1) wm = fmaxf(wm, __shfl_down(wm, off));
        if (lane == 0 && wave < 5) s_p5[wave] = wm;
        __syncthreads();
        if (t == 0)
            s_one[0] = fmaxf(fmaxf(fmaxf(s_p5[0], s_p5[1]), fmaxf(s_p5[2], s_p5[3])), s_p5[4]);
        __syncthreads();
        const float mx = s_one[0];
        float e = (t < SMAX) ? __expf(m - mx) : 0.f;
        #pragma unroll
        for (int off = 32; off > 0; off >>= 1) e += __shfl_down(e, off);
        if (lane == 0 && wave < 5) s_p5[wave] = e;
        __syncthreads();
        if (t == 0) {
            float s = s_p5[0] + s_p5[1] + s_p5[2] + s_p5[3] + s_p5[4];
            int nb = n_particles[b];
            float loss = -(s_m[nb] - mx - __logf(s));
            atomicAdd(out, loss * (1.0f / BQ));
        }
    }
}

// ---------------------------------------------------------------------------
// Finisher: combine the 2 row-half col-min partials per batch, sum -> out.
// 128 blocks x 256 threads.
// ---------------------------------------------------------------------------
__global__ __launch_bounds__(256) void finish_kernel(
    const float* __restrict__ ws, float* __restrict__ out)
{
    const int b = blockIdx.x;
    const int t = threadIdx.x;
    __shared__ float s_p[4];
    float v = fminf(ws[(b*2)*NQ + t], ws[(b*2+1)*NQ + t]);
    #pragma unroll
    for (int off = 32; off > 0; off >>= 1) v += __shfl_down(v, off, 64);
    if ((t & 63) == 0) s_p[t >> 6] = v;
    __syncthreads();
    if (t == 0)
        atomicAdd(out, (s_p[0] + s_p[1] + s_p[2] + s_p[3]) * (1.0f / BQ));
}

extern "C" void kernel_launch(void* const* d_in, const int* in_sizes, int n_in,
                              void* d_out, int out_size, void* d_ws, size_t ws_size,
                              hipStream_t stream) {
    (void)in_sizes; (void)n_in; (void)ws_size;
    const int*   p_class     = (const int*)d_in[0];
    const int*   p_charge    = (const int*)d_in[1];
    const int*   n_particles = (const int*)d_in[2];
    const float* cls_logits  = (const float*)d_in[3];
    const float* chg_logits  = (const float*)d_in[4];
    const float* p_pos       = (const float*)d_in[5];
    const float* pf_pos      = (const float*)d_in[6];
    const float* p_mom       = (const float*)d_in[7];
    const float* pf_mom      = (const float*)d_in[8];
    const float* p_en        = (const float*)d_in[9];
    const float* pf_en       = (const float*)d_in[10];
    const float* setsizes    = (const float*)d_in[11];
    float* out = (float*)d_out;
    float* ws  = (float*)d_ws;   // needs 256*256*4 = 256 KB

    (void)hipMemsetAsync(out, 0, sizeof(float) * (size_t)out_size, stream);

    main_kernel<<<NMAIN, 512, 0, stream>>>(
        p_class, p_charge, n_particles, cls_logits, chg_logits,
        p_pos, pf_pos, p_mom, pf_mom, p_en, pf_en, setsizes, ws, out);

    finish_kernel<<<BQ, 256, 0, stream>>>(ws, out);
}